// Round 1
// baseline (308.491 us; speedup 1.0000x reference)
//
#include <hip/hip_runtime.h>
#include <hip/hip_bf16.h>

// Problem constants: N tokens, D d_model, E experts, H hidden, K top-k
#define NTOK 4096
#define DM   512
#define NE   32
#define HD   128
#define TK   4

typedef unsigned short u16;
typedef unsigned int   u32;
typedef u16   u16x4 __attribute__((ext_vector_type(4)));
typedef u16   u16x8 __attribute__((ext_vector_type(8)));
typedef short short8 __attribute__((ext_vector_type(8)));
typedef float f32x4 __attribute__((ext_vector_type(4)));
typedef float f32x4v __attribute__((ext_vector_type(4)));
typedef u32   u32x4 __attribute__((ext_vector_type(4)));

__device__ __forceinline__ u16 f2bf(float f) {
    union { float f; u32 u; } v; v.f = f;
    u32 u = v.u;
    u32 r = (u + 0x7FFFu + ((u >> 16) & 1u)) >> 16;   // RNE
    return (u16)r;
}

// ---------------- x fp32 -> bf16 (same layout) ----------------
__global__ __launch_bounds__(256) void cvt_x_kernel(const float* __restrict__ in,
                                                    u16* __restrict__ out) {
    int idx = blockIdx.x * 256 + threadIdx.x;       // 524288 threads, 4 elems each
    f32x4 v = *(const f32x4*)(in + (size_t)idx * 4);
    u16x4 h;
    h[0] = f2bf(v[0]); h[1] = f2bf(v[1]); h[2] = f2bf(v[2]); h[3] = f2bf(v[3]);
    *(u16x4*)(out + (size_t)idx * 4) = h;
}

// -------- batched transpose + convert: in[e][Rin][Cin] f32 -> out[e][Cin][Rin] bf16 --------
__global__ __launch_bounds__(256) void transpose_cvt_kernel(const float* __restrict__ in,
                                                            u16* __restrict__ out,
                                                            int Rin, int Cin) {
    __shared__ __align__(16) u16 t[64][72];         // +8 pad
    int e = blockIdx.z;
    int r0 = blockIdx.y * 64, c0 = blockIdx.x * 64;
    const float* inp = in + (size_t)e * Rin * Cin;
    u16* outp = out + (size_t)e * Rin * Cin;
    int tid = threadIdx.x;
#pragma unroll
    for (int rep = 0; rep < 16; ++rep) {
        int id = tid + 256 * rep;
        int r = id >> 6, c = id & 63;
        t[r][c] = f2bf(inp[(size_t)(r0 + r) * Cin + (c0 + c)]);
    }
    __syncthreads();
#pragma unroll
    for (int rep = 0; rep < 2; ++rep) {
        int ch = tid + 256 * rep;                   // 512 chunks of 8
        int cc = ch >> 3;
        int rr0 = (ch & 7) * 8;
        u16x8 v;
#pragma unroll
        for (int j = 0; j < 8; ++j) v[j] = t[rr0 + j][cc];
        *(u16x8*)(outp + (size_t)(c0 + cc) * Rin + (r0 + rr0)) = v;
    }
}

// ---------------- router: fp64 logits, top-4, build expert lists ----------------
__global__ __launch_bounds__(256) void router_kernel(const float* __restrict__ x,
                                                     const float* __restrict__ sel,
                                                     int* __restrict__ counts,
                                                     int* __restrict__ tok_list,
                                                     float* __restrict__ gate_list) {
    __shared__ double s_logit[16][33];
    int tid = threadIdx.x;
    int wv = tid >> 6, lane = tid & 63;
    int tb = blockIdx.x * 16 + wv * 4;              // 4 tokens per wave

    f32x4 xa[4][2];
#pragma unroll
    for (int tt = 0; tt < 4; ++tt) {
        const float* xr = x + (size_t)(tb + tt) * DM + lane * 8;
        xa[tt][0] = *(const f32x4*)xr;
        xa[tt][1] = *(const f32x4*)(xr + 4);
    }
    for (int e = 0; e < NE; ++e) {
        const float* sr = sel + (size_t)e * DM + lane * 8;
        f32x4 s0 = *(const f32x4*)sr;
        f32x4 s1 = *(const f32x4*)(sr + 4);
#pragma unroll
        for (int tt = 0; tt < 4; ++tt) {
            double p = 0.0;
#pragma unroll
            for (int j = 0; j < 4; ++j) p = fma((double)xa[tt][0][j], (double)s0[j], p);
#pragma unroll
            for (int j = 0; j < 4; ++j) p = fma((double)xa[tt][1][j], (double)s1[j], p);
#pragma unroll
            for (int off = 32; off; off >>= 1) p += __shfl_xor(p, off);
            if (lane == 0) s_logit[wv * 4 + tt][e] = p;
        }
    }
    __syncthreads();
    if (tid < 16) {
        int t = blockIdx.x * 16 + tid;
        unsigned mask = 0;
        for (int k = 0; k < TK; ++k) {
            double best = -1e300; int be = 0;
            for (int e = 0; e < NE; ++e) {
                double v = s_logit[tid][e];
                if (!((mask >> e) & 1u) && v > best) { best = v; be = e; }
            }
            mask |= 1u << be;
            float gate = (float)(1.0 / (1.0 + exp(-best)));
            int pos = atomicAdd(&counts[be], 1);
            tok_list[(size_t)be * NTOK + pos] = t;
            gate_list[(size_t)be * NTOK + pos] = gate;
        }
    }
}

// ---------------- fused expert MLP: per (expert, 64-token tile) ----------------
// GEMM1: [64 x 512] @ W1t[e] ([H][D] layout, as Bt) -> relu*gate -> Hm [64 x 128]
// GEMM2: Hm @ W2t[e] ([D][H] layout) -> atomicAdd into out
__global__ __launch_bounds__(256) void moe_mlp_kernel(const u16* __restrict__ xbf,
                                                      const u16* __restrict__ w1t,
                                                      const u16* __restrict__ w2t,
                                                      const int* __restrict__ counts,
                                                      const int* __restrict__ tok_list,
                                                      const float* __restrict__ gate_list,
                                                      float* __restrict__ out) {
    int e = blockIdx.y;
    int cnt = counts[e];
    int t0 = blockIdx.x * 64;
    if (t0 >= cnt) return;

    __shared__ __align__(16) u16 A_lds[64][56];   // 32 used cols, stride 112B (16B mult, 2-way banks)
    __shared__ __align__(16) u16 B_lds[128][56];
    __shared__ __align__(16) u16 Hm[64][136];     // stride 272B
    __shared__ int   s_tok[64];
    __shared__ float s_gate[64];

    int tid = threadIdx.x;
    int wv = tid >> 6, lane = tid & 63;
    int m = lane & 15, q = lane >> 4;

    if (tid < 64) {
        int idx = t0 + tid;
        bool valid = idx < cnt;
        s_tok[tid]  = tok_list[(size_t)e * NTOK + (valid ? idx : t0)];
        s_gate[tid] = valid ? gate_list[(size_t)e * NTOK + idx] : 0.0f;
    }
    __syncthreads();

    // staging roles
    int a_slot = tid >> 2, a_c = (tid & 3) * 8;
    const u16* a_src = xbf + (size_t)s_tok[a_slot] * DM + a_c;
    const u16* w1e = w1t + (size_t)e * HD * DM;   // [h][d]
    const u16* w2e = w2t + (size_t)e * DM * HD;   // [v][h]
    int ch1 = tid, ch2 = tid + 256;
    int b1r = ch1 >> 2, b1c = (ch1 & 3) * 8;
    int b2r = ch2 >> 2, b2c = (ch2 & 3) * 8;

    f32x4 acc[8];
#pragma unroll
    for (int n = 0; n < 8; ++n) acc[n] = (f32x4){0.f, 0.f, 0.f, 0.f};

    for (int ks = 0; ks < 16; ++ks) {
        int k0 = ks * 32;
        u32x4 av  = *(const u32x4*)(a_src + k0);
        u32x4 bv1 = *(const u32x4*)(w1e + (size_t)b1r * DM + k0 + b1c);
        u32x4 bv2 = *(const u32x4*)(w1e + (size_t)b2r * DM + k0 + b2c);
        __syncthreads();                          // prior tile fully consumed
        *(u32x4*)&A_lds[a_slot][a_c] = av;
        *(u32x4*)&B_lds[b1r][b1c] = bv1;
        *(u32x4*)&B_lds[b2r][b2c] = bv2;
        __syncthreads();
        short8 a = *(const short8*)&A_lds[16 * wv + m][q * 8];
#pragma unroll
        for (int n = 0; n < 8; ++n) {
            short8 b = *(const short8*)&B_lds[16 * n + m][q * 8];
            acc[n] = __builtin_amdgcn_mfma_f32_16x16x32_bf16(a, b, acc[n], 0, 0, 0);
        }
    }

    // relu * gate -> Hm (each wave writes only its own 16 rows)
    int rowslot[4]; float gv[4]; int tks[4];
#pragma unroll
    for (int r = 0; r < 4; ++r) {
        rowslot[r] = 16 * wv + q * 4 + r;
        gv[r]  = s_gate[rowslot[r]];
        tks[r] = s_tok[rowslot[r]];
    }
#pragma unroll
    for (int n = 0; n < 8; ++n)
#pragma unroll
        for (int r = 0; r < 4; ++r) {
            float v = fmaxf(acc[n][r], 0.0f) * gv[r];
            Hm[rowslot[r]][16 * n + m] = f2bf(v);
        }

    // GEMM2: 4 column groups of 128
    for (int vg = 0; vg < 4; ++vg) {
        int v0 = vg * 128;
        f32x4 acc2[8];
#pragma unroll
        for (int n = 0; n < 8; ++n) acc2[n] = (f32x4){0.f, 0.f, 0.f, 0.f};
        for (int ks = 0; ks < 4; ++ks) {
            int k0 = ks * 32;
            u32x4 bv1 = *(const u32x4*)(w2e + (size_t)(v0 + b1r) * HD + k0 + b1c);
            u32x4 bv2 = *(const u32x4*)(w2e + (size_t)(v0 + b2r) * HD + k0 + b2c);
            __syncthreads();                      // B_lds free (covers GEMM1 readers too)
            *(u32x4*)&B_lds[b1r][b1c] = bv1;
            *(u32x4*)&B_lds[b2r][b2c] = bv2;
            __syncthreads();
            short8 a2 = *(const short8*)&Hm[16 * wv + m][k0 + q * 8];
#pragma unroll
            for (int n = 0; n < 8; ++n) {
                short8 b2 = *(const short8*)&B_lds[16 * n + m][q * 8];
                acc2[n] = __builtin_amdgcn_mfma_f32_16x16x32_bf16(a2, b2, acc2[n], 0, 0, 0);
            }
        }
#pragma unroll
        for (int n = 0; n < 8; ++n)
#pragma unroll
            for (int r = 0; r < 4; ++r)
                atomicAdd(&out[(size_t)tks[r] * DM + v0 + 16 * n + m], acc2[n][r]);
    }
}

extern "C" void kernel_launch(void* const* d_in, const int* in_sizes, int n_in,
                              void* d_out, int out_size, void* d_ws, size_t ws_size,
                              hipStream_t stream) {
    const float* x   = (const float*)d_in[0];   // [N, D]
    const float* sel = (const float*)d_in[1];   // [E, D]
    const float* w1  = (const float*)d_in[2];   // [E, D, H]
    const float* w2  = (const float*)d_in[3];   // [E, H, D]
    float* out = (float*)d_out;                 // [N, D]

    char* ws = (char*)d_ws;
    int*   counts    = (int*)(ws);                                  // 128 B (pad 256)
    int*   tok_list  = (int*)(ws + 256);                            // E*N*4 = 512 KB
    float* gate_list = (float*)(ws + 256 + (size_t)NE * NTOK * 4);  // 512 KB
    u16*   xbf = (u16*)(ws + 256 + (size_t)NE * NTOK * 8);          // N*D*2 = 4 MB
    u16*   w1t = xbf + (size_t)NTOK * DM;                           // E*H*D*2 = 4 MB
    u16*   w2t = w1t + (size_t)NE * HD * DM;                        // 4 MB

    hipMemsetAsync(counts, 0, NE * sizeof(int), stream);
    hipMemsetAsync(d_out, 0, (size_t)NTOK * DM * sizeof(float), stream);

    cvt_x_kernel<<<(NTOK * DM / 4) / 256, 256, 0, stream>>>(x, xbf);
    // w1 [E][512][128] -> w1t [E][128][512]
    transpose_cvt_kernel<<<dim3(HD / 64, DM / 64, NE), 256, 0, stream>>>(w1, w1t, DM, HD);
    // w2 [E][128][512] -> w2t [E][512][128]
    transpose_cvt_kernel<<<dim3(DM / 64, HD / 64, NE), 256, 0, stream>>>(w2, w2t, HD, DM);

    router_kernel<<<NTOK / 16, 256, 0, stream>>>(x, sel, counts, tok_list, gate_list);

    moe_mlp_kernel<<<dim3(NTOK / 64, NE), 256, 0, stream>>>(xbf, w1t, w2t, counts,
                                                            tok_list, gate_list, out);
}

// Round 2
// 278.829 us; speedup vs baseline: 1.1064x; 1.1064x over previous
//
#include <hip/hip_runtime.h>
#include <hip/hip_bf16.h>

// Problem constants: N tokens, D d_model, E experts, H hidden, K top-k
#define NTOK 4096
#define DM   512
#define NE   32
#define HD   128
#define TK   4

typedef unsigned short u16;
typedef unsigned int   u32;
typedef u16   u16x8 __attribute__((ext_vector_type(8)));
typedef short short8 __attribute__((ext_vector_type(8)));
typedef float f32x4 __attribute__((ext_vector_type(4)));

__device__ __forceinline__ u16 f2bf(float f) {
    union { float f; u32 u; } v; v.f = f;
    return (u16)((v.u + 0x7FFFu + ((v.u >> 16) & 1u)) >> 16);   // RNE
}

// ---------------- router: fp64 logits, top-4, build expert lists; also x -> bf16 ----------------
__global__ __launch_bounds__(256) void router_kernel(const float* __restrict__ x,
                                                     const float* __restrict__ sel,
                                                     int* __restrict__ counts,
                                                     int* __restrict__ tok_list,
                                                     float* __restrict__ gate_list,
                                                     u16* __restrict__ xbf) {
    __shared__ double s_logit[16][33];
    int tid = threadIdx.x;
    int wv = tid >> 6, lane = tid & 63;
    int tb = blockIdx.x * 16 + wv * 4;              // 4 tokens per wave

    f32x4 xa[4][2];
#pragma unroll
    for (int tt = 0; tt < 4; ++tt) {
        const float* xr = x + (size_t)(tb + tt) * DM + lane * 8;
        xa[tt][0] = *(const f32x4*)xr;
        xa[tt][1] = *(const f32x4*)(xr + 4);
    }
    // fused x -> bf16 conversion (each wave covers its 4 tokens fully)
#pragma unroll
    for (int tt = 0; tt < 4; ++tt) {
        u16x8 h;
#pragma unroll
        for (int j = 0; j < 4; ++j) { h[j] = f2bf(xa[tt][0][j]); h[4 + j] = f2bf(xa[tt][1][j]); }
        *(u16x8*)(xbf + (size_t)(tb + tt) * DM + lane * 8) = h;
    }
    for (int e = 0; e < NE; ++e) {
        const float* sr = sel + (size_t)e * DM + lane * 8;
        f32x4 s0 = *(const f32x4*)sr;
        f32x4 s1 = *(const f32x4*)(sr + 4);
#pragma unroll
        for (int tt = 0; tt < 4; ++tt) {
            double p = 0.0;
#pragma unroll
            for (int j = 0; j < 4; ++j) p = fma((double)xa[tt][0][j], (double)s0[j], p);
#pragma unroll
            for (int j = 0; j < 4; ++j) p = fma((double)xa[tt][1][j], (double)s1[j], p);
#pragma unroll
            for (int off = 32; off; off >>= 1) p += __shfl_xor(p, off);
            if (lane == 0) s_logit[wv * 4 + tt][e] = p;
        }
    }
    __syncthreads();
    if (tid < 16) {
        int t = blockIdx.x * 16 + tid;
        unsigned mask = 0;
        for (int k = 0; k < TK; ++k) {
            double best = -1e300; int be = 0;
            for (int e = 0; e < NE; ++e) {
                double v = s_logit[tid][e];
                if (!((mask >> e) & 1u) && v > best) { best = v; be = e; }
            }
            mask |= 1u << be;
            float gate = (float)(1.0 / (1.0 + exp(-best)));
            int pos = atomicAdd(&counts[be], 1);
            tok_list[(size_t)be * NTOK + pos] = t;
            gate_list[(size_t)be * NTOK + pos] = gate;
        }
    }
}

// ------- weight swizzle: fp32 [E][Kdim][Ndim] -> bf16 fragment-major ------------
// frag[wl][lane][j] = in[e][32*ks + (lane>>4)*8 + j][16*nt + (lane&15)]
// W1: Kdim=512, Ndim=128, wl = e*128 + ks*8  + nt  (4096 waves)
// W2: Kdim=128, Ndim=512, wl = e*128 + ks*32 + nt  (4096 waves)
__global__ __launch_bounds__(256) void swizzle_w_kernel(const float* __restrict__ w1,
                                                        const float* __restrict__ w2,
                                                        u16* __restrict__ wf1,
                                                        u16* __restrict__ wf2) {
    int tid = threadIdx.x;
    int w = blockIdx.x * 4 + (tid >> 6);
    int lane = tid & 63, m = lane & 15, q = lane >> 4;
    const float* in; u16* outp; int Nd;
    if (w < 4096) {
        int wl = w, e = wl >> 7, rem = wl & 127, ks = rem >> 3, nt = rem & 7;
        in = w1 + (size_t)e * DM * HD + (size_t)(32 * ks + q * 8) * HD + 16 * nt + m;
        Nd = HD;
        outp = wf1 + (size_t)wl * 512 + lane * 8;
    } else {
        int wl = w - 4096, e = wl >> 7, rem = wl & 127, ks = rem >> 5, nt = rem & 31;
        in = w2 + (size_t)e * HD * DM + (size_t)(32 * ks + q * 8) * DM + 16 * nt + m;
        Nd = DM;
        outp = wf2 + (size_t)wl * 512 + lane * 8;
    }
    u16x8 h;
#pragma unroll
    for (int j = 0; j < 8; ++j) h[j] = f2bf(in[(size_t)j * Nd]);
    *(u16x8*)outp = h;
}

// ------- tile list: compacted (expert, tile) work items; n_tiles <= 288 ----------
__global__ void build_tiles_kernel(const int* __restrict__ counts,
                                   int* __restrict__ tiles,
                                   int* __restrict__ n_tiles) {
    int lane = threadIdx.x;                         // 64 threads, first 32 active
    int c = (lane < NE) ? counts[lane] : 0;
    int nt = (c + 63) >> 6;
    int s = nt;
#pragma unroll
    for (int off = 1; off < 32; off <<= 1) {
        int v = __shfl_up(s, off);
        if (lane >= off) s += v;
    }
    int pre = s - nt;
    if (lane < NE) {
        for (int t = 0; t < nt; ++t) {
            int rows = c - t * 64; if (rows > 64) rows = 64;
            tiles[pre + t] = (lane << 20) | (t << 8) | rows;
        }
        if (lane == NE - 1) n_tiles[0] = s;
    }
}

// ---------------- fused expert MLP: barrier-free K-loops, fragment-major weights ----------------
__global__ __launch_bounds__(256) void moe_mlp_kernel(const u16* __restrict__ xbf,
                                                      const u16* __restrict__ wf1,
                                                      const u16* __restrict__ wf2,
                                                      const int* __restrict__ tok_list,
                                                      const float* __restrict__ gate_list,
                                                      const int* __restrict__ tiles,
                                                      const int* __restrict__ n_tiles,
                                                      float* __restrict__ out) {
    if ((int)blockIdx.x >= n_tiles[0]) return;
    int tile = tiles[blockIdx.x];
    int e = tile >> 20, t = (tile >> 8) & 0xFFF, rows = tile & 0xFF;

    __shared__ int   s_tok[64];
    __shared__ float s_gate[64];
    __shared__ __align__(16) u16 Hm[64][136];       // stride 272B: b128 reads 2-way (free)

    int tid = threadIdx.x;
    if (tid < 64) {
        int base = e * NTOK + t * 64;
        bool val = tid < rows;
        s_tok[tid]  = tok_list[base + (val ? tid : 0)];
        s_gate[tid] = val ? gate_list[base + tid] : 0.0f;
    }
    __syncthreads();

    int wv = tid >> 6, lane = tid & 63, m = lane & 15, q = lane >> 4;

    // A fragments to registers: 16 ksteps x 16B/lane (64-B coalesced gather)
    int myrow = s_tok[16 * wv + m];
    const u16* abase = xbf + (size_t)myrow * DM + q * 8;
    short8 afr[16];
#pragma unroll
    for (int ks = 0; ks < 16; ++ks) afr[ks] = *(const short8*)(abase + 32 * ks);

    // GEMM1: [64 x 512] @ W1 -> [64 x 128]; B direct from global, no barriers
    const u16* w1f = wf1 + (size_t)e * (128 * 512);
    f32x4 acc[8];
#pragma unroll
    for (int n = 0; n < 8; ++n) acc[n] = (f32x4){0.f, 0.f, 0.f, 0.f};
#pragma unroll 4
    for (int ks = 0; ks < 16; ++ks) {
        const u16* bp = w1f + (size_t)ks * (8 * 512) + lane * 8;
#pragma unroll
        for (int n = 0; n < 8; ++n) {
            short8 b = *(const short8*)(bp + n * 512);
            acc[n] = __builtin_amdgcn_mfma_f32_16x16x32_bf16(afr[ks], b, acc[n], 0, 0, 0);
        }
    }

    // relu * gate -> Hm (C-layout -> A-layout via LDS)
    int rs[4]; float gv[4]; int tk[4];
#pragma unroll
    for (int r = 0; r < 4; ++r) {
        rs[r] = 16 * wv + q * 4 + r;
        gv[r] = s_gate[rs[r]];
        tk[r] = s_tok[rs[r]];
    }
#pragma unroll
    for (int n = 0; n < 8; ++n)
#pragma unroll
        for (int r = 0; r < 4; ++r)
            Hm[rs[r]][16 * n + m] = f2bf(fmaxf(acc[n][r], 0.f) * gv[r]);
    __syncthreads();

    // GEMM2: [64 x 128] @ W2 -> [64 x 512]; B direct from global, no barriers
    const u16* w2f = wf2 + (size_t)e * (128 * 512);
#pragma unroll
    for (int vg = 0; vg < 4; ++vg) {
        f32x4 acc2[8];
#pragma unroll
        for (int n = 0; n < 8; ++n) acc2[n] = (f32x4){0.f, 0.f, 0.f, 0.f};
#pragma unroll
        for (int ks = 0; ks < 4; ++ks) {
            short8 a2 = *(const short8*)&Hm[16 * wv + m][32 * ks + q * 8];
            const u16* bp = w2f + (size_t)(ks * 32 + vg * 8) * 512 + lane * 8;
#pragma unroll
            for (int n = 0; n < 8; ++n) {
                short8 b = *(const short8*)(bp + n * 512);
                acc2[n] = __builtin_amdgcn_mfma_f32_16x16x32_bf16(a2, b, acc2[n], 0, 0, 0);
            }
        }
#pragma unroll
        for (int n = 0; n < 8; ++n)
#pragma unroll
            for (int r = 0; r < 4; ++r)
                atomicAdd(&out[(size_t)tk[r] * DM + vg * 128 + 16 * n + m], acc2[n][r]);
    }
}

extern "C" void kernel_launch(void* const* d_in, const int* in_sizes, int n_in,
                              void* d_out, int out_size, void* d_ws, size_t ws_size,
                              hipStream_t stream) {
    const float* x   = (const float*)d_in[0];   // [N, D]
    const float* sel = (const float*)d_in[1];   // [E, D]
    const float* w1  = (const float*)d_in[2];   // [E, D, H]
    const float* w2  = (const float*)d_in[3];   // [E, H, D]
    float* out = (float*)d_out;                 // [N, D]

    char* ws = (char*)d_ws;
    int*   counts    = (int*)(ws);                                   // @0, 256B
    int*   n_tiles   = (int*)(ws + 256);                             // @256
    int*   tiles     = (int*)(ws + 512);                             // @512, <=1.2KB
    int*   tok_list  = (int*)(ws + 2048);                            // 512KB
    float* gate_list = (float*)(ws + 2048 + (size_t)NE * NTOK * 4);  // 512KB
    u16*   xbf = (u16*)(ws + 2048 + (size_t)NE * NTOK * 8);          // 4MB
    u16*   wf1 = xbf + (size_t)NTOK * DM;                            // 4MB
    u16*   wf2 = wf1 + (size_t)NE * HD * DM;                         // 4MB

    hipMemsetAsync(counts, 0, 256, stream);
    hipMemsetAsync(d_out, 0, (size_t)NTOK * DM * sizeof(float), stream);

    router_kernel<<<NTOK / 16, 256, 0, stream>>>(x, sel, counts, tok_list, gate_list, xbf);
    swizzle_w_kernel<<<2048, 256, 0, stream>>>(w1, w2, wf1, wf2);
    build_tiles_kernel<<<1, 64, 0, stream>>>(counts, tiles, n_tiles);
    moe_mlp_kernel<<<288, 256, 0, stream>>>(xbf, wf1, wf2, tok_list, gate_list,
                                            tiles, n_tiles, out);
}

// Round 3
// 185.904 us; speedup vs baseline: 1.6594x; 1.4999x over previous
//
#include <hip/hip_runtime.h>
#include <hip/hip_bf16.h>

// Problem constants: N tokens, D d_model, E experts, H hidden, K top-k
#define NTOK 4096
#define DM   512
#define NE   32
#define HD   128
#define TK   4

typedef unsigned short u16;
typedef unsigned int   u32;
typedef u16   u16x8 __attribute__((ext_vector_type(8)));
typedef short short8 __attribute__((ext_vector_type(8)));
typedef float f32x4 __attribute__((ext_vector_type(4)));

__device__ __forceinline__ u16 f2bf(float f) {
    union { float f; u32 u; } v; v.f = f;
    return (u16)((v.u + 0x7FFFu + ((v.u >> 16) & 1u)) >> 16);   // RNE
}
__device__ __forceinline__ float bf2f(u16 h) {
    union { u32 u; float f; } v; v.u = ((u32)h) << 16; return v.f;
}

// ---------------- fused prep: blocks [0,256) router + x->bf16; [256,2304) weight swizzle --------
// swizzle: fp32 [E][Kdim][Ndim] -> bf16 fragment-major:
//   frag[wl][lane][j] = in[e][32*ks + (lane>>4)*8 + j][16*nt + (lane&15)]
__global__ __launch_bounds__(256) void prep_kernel(const float* __restrict__ x,
                                                   const float* __restrict__ sel,
                                                   const float* __restrict__ w1,
                                                   const float* __restrict__ w2,
                                                   int* __restrict__ counts,
                                                   int* __restrict__ tok_list,
                                                   float* __restrict__ gate_list,
                                                   u16* __restrict__ xbf,
                                                   u16* __restrict__ wf1,
                                                   u16* __restrict__ wf2) {
    int tid = threadIdx.x;
    int wv = tid >> 6, lane = tid & 63;

    if (blockIdx.x >= 256) {
        // ---- weight swizzle ----
        int w = (blockIdx.x - 256) * 4 + wv;        // 0..8191
        int m = lane & 15, q = lane >> 4;
        const float* in; u16* outp; int Nd;
        if (w < 4096) {
            int e = w >> 7, rem = w & 127, ks = rem >> 3, nt = rem & 7;
            in = w1 + (size_t)e * DM * HD + (size_t)(32 * ks + q * 8) * HD + 16 * nt + m;
            Nd = HD;
            outp = wf1 + (size_t)w * 512 + lane * 8;
        } else {
            int wl = w - 4096, e = wl >> 7, rem = wl & 127, ks = rem >> 5, nt = rem & 31;
            in = w2 + (size_t)e * HD * DM + (size_t)(32 * ks + q * 8) * DM + 16 * nt + m;
            Nd = DM;
            outp = wf2 + (size_t)wl * 512 + lane * 8;
        }
        u16x8 h;
#pragma unroll
        for (int j = 0; j < 8; ++j) h[j] = f2bf(in[(size_t)j * Nd]);
        *(u16x8*)outp = h;
        return;
    }

    // ---- router: fp64 logits, top-4; fused x->bf16 ----
    __shared__ double s_logit[16][33];
    int tb = blockIdx.x * 16 + wv * 4;              // 4 tokens per wave

    f32x4 xa[4][2];
#pragma unroll
    for (int tt = 0; tt < 4; ++tt) {
        const float* xr = x + (size_t)(tb + tt) * DM + lane * 8;
        xa[tt][0] = *(const f32x4*)xr;
        xa[tt][1] = *(const f32x4*)(xr + 4);
    }
#pragma unroll
    for (int tt = 0; tt < 4; ++tt) {
        u16x8 h;
#pragma unroll
        for (int j = 0; j < 4; ++j) { h[j] = f2bf(xa[tt][0][j]); h[4 + j] = f2bf(xa[tt][1][j]); }
        *(u16x8*)(xbf + (size_t)(tb + tt) * DM + lane * 8) = h;
    }
    for (int e = 0; e < NE; ++e) {
        const float* sr = sel + (size_t)e * DM + lane * 8;
        f32x4 s0 = *(const f32x4*)sr;
        f32x4 s1 = *(const f32x4*)(sr + 4);
#pragma unroll
        for (int tt = 0; tt < 4; ++tt) {
            double p = 0.0;
#pragma unroll
            for (int j = 0; j < 4; ++j) p = fma((double)xa[tt][0][j], (double)s0[j], p);
#pragma unroll
            for (int j = 0; j < 4; ++j) p = fma((double)xa[tt][1][j], (double)s1[j], p);
#pragma unroll
            for (int off = 32; off; off >>= 1) p += __shfl_xor(p, off);
            if (lane == 0) s_logit[wv * 4 + tt][e] = p;
        }
    }
    __syncthreads();
    if (tid < 16) {
        int t = blockIdx.x * 16 + tid;
        unsigned mask = 0;
        for (int k = 0; k < TK; ++k) {
            double best = -1e300; int be = 0;
            for (int e = 0; e < NE; ++e) {
                double v = s_logit[tid][e];
                if (!((mask >> e) & 1u) && v > best) { best = v; be = e; }
            }
            mask |= 1u << be;
            float gate = 1.0f / (1.0f + __expf(-(float)best));
            int pos = atomicAdd(&counts[be], 1);
            tok_list[(size_t)be * NTOK + pos]  = (k << 16) | t;   // slot in high bits
            gate_list[(size_t)be * NTOK + pos] = gate;
        }
    }
}

// ---------------- fused expert MLP: reg-double-buffered B, no atomics (part path) ----------------
__global__ __launch_bounds__(256, 2) void moe_mlp_kernel(const u16* __restrict__ xbf,
                                                         const u16* __restrict__ wf1,
                                                         const u16* __restrict__ wf2,
                                                         const int* __restrict__ counts,
                                                         const int* __restrict__ tok_list,
                                                         const float* __restrict__ gate_list,
                                                         u16* __restrict__ part,
                                                         float* __restrict__ out,
                                                         int use_part) {
    // tile decode: scan counts (L2-broadcast, 32 iters)
    int b = blockIdx.x;
    int e = -1, t = 0, rows = 0, pre = 0;
    for (int ee = 0; ee < NE; ++ee) {
        int c = counts[ee];
        int nt = (c + 63) >> 6;
        if (e < 0 && b < pre + nt) { e = ee; t = b - pre; rows = c - t * 64; if (rows > 64) rows = 64; }
        pre += nt;
    }
    if (e < 0) return;

    __shared__ int   s_ent[64];
    __shared__ float s_gate[64];
    __shared__ __align__(16) u16 Hm[64][136];       // stride 272B: b128 reads 2-way (free)

    int tid = threadIdx.x;
    if (tid < 64) {
        int base = e * NTOK + t * 64;
        bool val = tid < rows;
        s_ent[tid]  = tok_list[base + (val ? tid : 0)];
        s_gate[tid] = val ? gate_list[base + tid] : 0.0f;
    }
    __syncthreads();

    int wv = tid >> 6, lane = tid & 63, m = lane & 15, q = lane >> 4;

    // A fragments: 16 ksteps x 16B/lane
    int myent = s_ent[16 * wv + m];
    const u16* abase = xbf + (size_t)(myent & 0xFFFF) * DM + q * 8;
    short8 afr[16];
#pragma unroll
    for (int ks = 0; ks < 16; ++ks) afr[ks] = *(const short8*)(abase + 32 * ks);

    // GEMM1: [64 x 512] @ W1 -> [64 x 128]; B double-buffered in registers
    const u16* w1f = wf1 + (size_t)e * (128 * 512);
    f32x4 acc[8];
#pragma unroll
    for (int n = 0; n < 8; ++n) acc[n] = (f32x4){0.f, 0.f, 0.f, 0.f};
    short8 bb[2][8];
#pragma unroll
    for (int n = 0; n < 8; ++n) bb[0][n] = *(const short8*)(w1f + n * 512 + lane * 8);
#pragma unroll
    for (int ks = 0; ks < 16; ++ks) {
        int cur = ks & 1, nxt = cur ^ 1;
        if (ks < 15) {
            const u16* bp = w1f + (size_t)(ks + 1) * 4096 + lane * 8;
#pragma unroll
            for (int n = 0; n < 8; ++n) bb[nxt][n] = *(const short8*)(bp + n * 512);
        }
#pragma unroll
        for (int n = 0; n < 8; ++n)
            acc[n] = __builtin_amdgcn_mfma_f32_16x16x32_bf16(afr[ks], bb[cur][n], acc[n], 0, 0, 0);
    }

    // relu * gate -> Hm (C-layout -> A-layout via LDS)
    int rs[4]; float gv[4]; int tk[4]; int sl[4];
#pragma unroll
    for (int r = 0; r < 4; ++r) {
        rs[r] = 16 * wv + q * 4 + r;
        gv[r] = s_gate[rs[r]];
        int en = s_ent[rs[r]];
        tk[r] = en & 0xFFFF; sl[r] = en >> 16;
    }
#pragma unroll
    for (int n = 0; n < 8; ++n)
#pragma unroll
        for (int r = 0; r < 4; ++r)
            Hm[rs[r]][16 * n + m] = f2bf(fmaxf(acc[n][r], 0.f) * gv[r]);
    __syncthreads();

    // GEMM2: [64 x 128] @ W2 -> [64 x 512]; flattened (vg,ks), B double-buffered
    const u16* w2f = wf2 + (size_t)e * (128 * 512);
    short8 cb[2][8];
#pragma unroll
    for (int n = 0; n < 8; ++n) cb[0][n] = *(const short8*)(w2f + n * 512 + lane * 8);
    f32x4 acc2[8];
#pragma unroll
    for (int n = 0; n < 8; ++n) acc2[n] = (f32x4){0.f, 0.f, 0.f, 0.f};
#pragma unroll
    for (int s = 0; s < 16; ++s) {
        int vg = s >> 2, ks = s & 3, cur = s & 1, nxt = cur ^ 1;
        if (s < 15) {
            int s2 = s + 1, vg2 = s2 >> 2, ks2 = s2 & 3;
            const u16* bp = w2f + (size_t)(ks2 * 32 + vg2 * 8) * 512 + lane * 8;
#pragma unroll
            for (int n = 0; n < 8; ++n) cb[nxt][n] = *(const short8*)(bp + n * 512);
        }
        short8 a2 = *(const short8*)&Hm[16 * wv + m][32 * ks + q * 8];
#pragma unroll
        for (int n = 0; n < 8; ++n)
            acc2[n] = __builtin_amdgcn_mfma_f32_16x16x32_bf16(a2, cb[cur][n], acc2[n], 0, 0, 0);
        if (ks == 3) {
            if (use_part) {
#pragma unroll
                for (int n = 0; n < 8; ++n)
#pragma unroll
                    for (int r = 0; r < 4; ++r)
                        if (rs[r] < rows)
                            part[((size_t)sl[r] * NTOK + tk[r]) * DM + vg * 128 + 16 * n + m] =
                                f2bf(acc2[n][r]);
            } else {
#pragma unroll
                for (int n = 0; n < 8; ++n)
#pragma unroll
                    for (int r = 0; r < 4; ++r)
                        if (rs[r] < rows)
                            atomicAdd(&out[(size_t)tk[r] * DM + vg * 128 + 16 * n + m], acc2[n][r]);
            }
#pragma unroll
            for (int n = 0; n < 8; ++n) acc2[n] = (f32x4){0.f, 0.f, 0.f, 0.f};
        }
    }
}

// ---------------- combine: out[t][c] = sum_k part[k][t][c] ----------------
__global__ __launch_bounds__(256) void combine_kernel(const u16* __restrict__ part,
                                                      float* __restrict__ out) {
    size_t off = ((size_t)blockIdx.x * 256 + threadIdx.x) * 8;
    float s[8] = {0, 0, 0, 0, 0, 0, 0, 0};
#pragma unroll
    for (int k = 0; k < TK; ++k) {
        u16x8 p = *(const u16x8*)(part + (size_t)k * NTOK * DM + off);
#pragma unroll
        for (int j = 0; j < 8; ++j) s[j] += bf2f(p[j]);
    }
    *(f32x4*)(out + off)     = (f32x4){s[0], s[1], s[2], s[3]};
    *(f32x4*)(out + off + 4) = (f32x4){s[4], s[5], s[6], s[7]};
}

extern "C" void kernel_launch(void* const* d_in, const int* in_sizes, int n_in,
                              void* d_out, int out_size, void* d_ws, size_t ws_size,
                              hipStream_t stream) {
    const float* x   = (const float*)d_in[0];   // [N, D]
    const float* sel = (const float*)d_in[1];   // [E, D]
    const float* w1  = (const float*)d_in[2];   // [E, D, H]
    const float* w2  = (const float*)d_in[3];   // [E, H, D]
    float* out = (float*)d_out;                 // [N, D]

    char* ws = (char*)d_ws;
    int*   counts    = (int*)(ws);                                   // 256B
    int*   tok_list  = (int*)(ws + 2048);                            // 512KB (slot<<16 | tok)
    float* gate_list = (float*)(ws + 2048 + (size_t)NE * NTOK * 4);  // 512KB
    u16*   xbf  = (u16*)(ws + 2048 + (size_t)NE * NTOK * 8);         // 4MB
    u16*   wf1  = xbf + (size_t)NTOK * DM;                           // 4MB
    u16*   wf2  = wf1 + (size_t)NE * HD * DM;                        // 4MB
    u16*   part = wf2 + (size_t)NE * HD * DM;                        // 16.8MB (optional)

    size_t need = 2048 + (size_t)NE * NTOK * 8 + (size_t)NTOK * DM * 2
                + 2 * (size_t)NE * HD * DM * 2 + (size_t)TK * NTOK * DM * 2;
    int use_part = (ws_size >= need) ? 1 : 0;

    hipMemsetAsync(counts, 0, 256, stream);
    if (!use_part)
        hipMemsetAsync(d_out, 0, (size_t)NTOK * DM * sizeof(float), stream);

    prep_kernel<<<2304, 256, 0, stream>>>(x, sel, w1, w2, counts, tok_list, gate_list,
                                          xbf, wf1, wf2);
    moe_mlp_kernel<<<288, 256, 0, stream>>>(xbf, wf1, wf2, counts, tok_list, gate_list,
                                            part, out, use_part);
    if (use_part)
        combine_kernel<<<NTOK * DM / 8 / 256, 256, 0, stream>>>(part, out);
}

// Round 4
// 151.773 us; speedup vs baseline: 2.0326x; 1.2249x over previous
//
#include <hip/hip_runtime.h>
#include <hip/hip_bf16.h>

// Problem constants: N tokens, D d_model, E experts, H hidden, K top-k
#define NTOK 4096
#define DM   512
#define NE   32
#define HD   128
#define TK   4

typedef unsigned short u16;
typedef unsigned int   u32;
typedef u16   u16x4 __attribute__((ext_vector_type(4)));
typedef u16   u16x8 __attribute__((ext_vector_type(8)));
typedef short short8 __attribute__((ext_vector_type(8)));
typedef float f32x4 __attribute__((ext_vector_type(4)));

__device__ __forceinline__ u16 f2bf(float f) {
    union { float f; u32 u; } v; v.f = f;
    return (u16)((v.u + 0x7FFFu + ((v.u >> 16) & 1u)) >> 16);   // RNE
}
__device__ __forceinline__ float bf2f(u16 h) {
    union { u32 u; float f; } v; v.u = ((u32)h) << 16; return v.f;
}

// ---------------- fused prep ----------------
// blocks [0,256):    router (thread-per-dot fp64, no cross-lane chains) + x->bf16
// blocks [256,2304): weight swizzle fp32 [E][Kdim][Ndim] -> bf16 fragment-major:
//   frag[wl][lane][j] = in[e][32*ks + (lane>>4)*8 + j][16*nt + (lane&15)]
__global__ __launch_bounds__(256) void prep_kernel(const float* __restrict__ x,
                                                   const float* __restrict__ sel,
                                                   const float* __restrict__ w1,
                                                   const float* __restrict__ w2,
                                                   int* __restrict__ counts,
                                                   int* __restrict__ tok_list,
                                                   float* __restrict__ gate_list,
                                                   u16* __restrict__ xbf,
                                                   u16* __restrict__ wf1,
                                                   u16* __restrict__ wf2) {
    int tid = threadIdx.x;
    int wv = tid >> 6, lane = tid & 63;

    if (blockIdx.x >= 256) {
        // ---- weight swizzle ----
        int w = (blockIdx.x - 256) * 4 + wv;        // 0..8191
        int m = lane & 15, q = lane >> 4;
        const float* in; u16* outp; int Nd;
        if (w < 4096) {
            int e = w >> 7, rem = w & 127, ks = rem >> 3, nt = rem & 7;
            in = w1 + (size_t)e * DM * HD + (size_t)(32 * ks + q * 8) * HD + 16 * nt + m;
            Nd = HD;
            outp = wf1 + (size_t)w * 512 + lane * 8;
        } else {
            int wl = w - 4096, e = wl >> 7, rem = wl & 127, ks = rem >> 5, nt = rem & 31;
            in = w2 + (size_t)e * HD * DM + (size_t)(32 * ks + q * 8) * DM + 16 * nt + m;
            Nd = DM;
            outp = wf2 + (size_t)wl * 512 + lane * 8;
        }
        u16x8 h;
#pragma unroll
        for (int j = 0; j < 8; ++j) h[j] = f2bf(in[(size_t)j * Nd]);
        *(u16x8*)outp = h;
        return;
    }

    // ---- router ----
    __shared__ float  xs[16][516];                  // stride 516 breaks bank aliasing
    __shared__ double sc[16][33];
    int tb = blockIdx.x * 16;

    // stage x -> LDS fp32, and write xbf (bf16) on the way
#pragma unroll
    for (int rep = 0; rep < 8; ++rep) {
        int idx = rep * 1024 + tid * 4;             // element in 16x512 tile
        int row = idx >> 9, col = idx & 511;
        f32x4 v = *(const f32x4*)(x + (size_t)(tb + row) * DM + col);
        *(f32x4*)&xs[row][col] = v;
        u16x4 h;
#pragma unroll
        for (int j = 0; j < 4; ++j) h[j] = f2bf(v[j]);
        *(u16x4*)(xbf + (size_t)(tb + row) * DM + col) = h;
    }
    __syncthreads();

    // each thread: 2 independent fp64 dot products (token, expert eg / eg+16)
    int tok = tid & 15, eg = tid >> 4;
    const float* se0 = sel + (size_t)eg * DM;
    const float* se1 = sel + (size_t)(eg + 16) * DM;
    double p0a = 0.0, p0b = 0.0, p1a = 0.0, p1b = 0.0;
#pragma unroll 4
    for (int j = 0; j < DM; j += 8) {
        f32x4 xv0 = *(const f32x4*)&xs[tok][j];
        f32x4 xv1 = *(const f32x4*)&xs[tok][j + 4];
        f32x4 sa0 = *(const f32x4*)(se0 + j);
        f32x4 sa1 = *(const f32x4*)(se0 + j + 4);
        f32x4 sb0 = *(const f32x4*)(se1 + j);
        f32x4 sb1 = *(const f32x4*)(se1 + j + 4);
#pragma unroll
        for (int k = 0; k < 4; ++k) {
            p0a = fma((double)xv0[k], (double)sa0[k], p0a);
            p0b = fma((double)xv1[k], (double)sa1[k], p0b);
            p1a = fma((double)xv0[k], (double)sb0[k], p1a);
            p1b = fma((double)xv1[k], (double)sb1[k], p1b);
        }
    }
    sc[tok][eg]      = p0a + p0b;
    sc[tok][eg + 16] = p1a + p1b;
    __syncthreads();

    if (tid < 16) {
        int t = tb + tid;
        unsigned mask = 0;
        for (int k = 0; k < TK; ++k) {
            double best = -1e300; int be = 0;
            for (int e = 0; e < NE; ++e) {
                double v = sc[tid][e];
                if (!((mask >> e) & 1u) && v > best) { best = v; be = e; }
            }
            mask |= 1u << be;
            float gate = 1.0f / (1.0f + __expf(-(float)best));
            int pos = atomicAdd(&counts[be], 1);
            tok_list[(size_t)be * NTOK + pos]  = (k << 16) | t;   // slot in high bits
            gate_list[(size_t)be * NTOK + pos] = gate;
        }
    }
}

// ---------------- fused expert MLP ----------------
// per (expert, 64-token tile); GEMM1 waves split 2x2 (rows x cols), paired-k double
// buffer; GEMM2 each wave owns a distinct 128-col group, all B up-front.
__global__ __launch_bounds__(256, 2) void moe_mlp_kernel(const u16* __restrict__ xbf,
                                                         const u16* __restrict__ wf1,
                                                         const u16* __restrict__ wf2,
                                                         const int* __restrict__ counts,
                                                         const int* __restrict__ tok_list,
                                                         const float* __restrict__ gate_list,
                                                         u16* __restrict__ part,
                                                         float* __restrict__ out,
                                                         int use_part) {
    int b = blockIdx.x;
    int e = -1, t = 0, rows = 0, pre = 0;
    for (int ee = 0; ee < NE; ++ee) {
        int cc = counts[ee];
        int nt = (cc + 63) >> 6;
        if (e < 0 && b < pre + nt) { e = ee; t = b - pre; rows = cc - t * 64; if (rows > 64) rows = 64; }
        pre += nt;
    }
    if (e < 0) return;

    __shared__ int   s_ent[64];
    __shared__ float s_gate[64];
    __shared__ __align__(16) u16 Hm[64][136];       // 272B stride: 16B-aligned, ~2-way banks

    int tid = threadIdx.x;
    if (tid < 64) {
        int base = e * NTOK + t * 64;
        bool val = tid < rows;
        s_ent[tid]  = tok_list[base + (val ? tid : 0)];
        s_gate[tid] = val ? gate_list[base + tid] : 0.0f;
    }
    __syncthreads();

    int wv = tid >> 6, lane = tid & 63, m = lane & 15, q = lane >> 4;
    int r = wv >> 1, c = wv & 1;                    // GEMM1: rows 32r..+32, cols 64c..+64
    const u16* w1f = wf1 + (size_t)e * (128 * 512);
    const u16* w2f = wf2 + (size_t)e * (128 * 512);

    const u16* a0 = xbf + (size_t)(s_ent[32 * r + m] & 0xFFFF) * DM + q * 8;
    const u16* a1 = xbf + (size_t)(s_ent[32 * r + 16 + m] & 0xFFFF) * DM + q * 8;

    // GEMM1: k-steps in pairs, double-buffered (12 loads in flight)
    short8 ab[2][2][2];                             // [buf][kk][mtile]
    short8 bb[2][2][4];                             // [buf][kk][ntile]
#pragma unroll
    for (int kk = 0; kk < 2; ++kk) {
        ab[0][kk][0] = *(const short8*)(a0 + 32 * kk);
        ab[0][kk][1] = *(const short8*)(a1 + 32 * kk);
        const u16* bp = w1f + (size_t)kk * 4096 + (size_t)(4 * c) * 512 + lane * 8;
#pragma unroll
        for (int n = 0; n < 4; ++n) bb[0][kk][n] = *(const short8*)(bp + n * 512);
    }
    f32x4 acc[2][4];
#pragma unroll
    for (int i = 0; i < 2; ++i)
#pragma unroll
        for (int n = 0; n < 4; ++n) acc[i][n] = (f32x4){0.f, 0.f, 0.f, 0.f};

#pragma unroll
    for (int kp = 0; kp < 8; ++kp) {
        int cur = kp & 1, nxt = cur ^ 1;
        if (kp < 7) {
            int ks0 = 2 * (kp + 1);
#pragma unroll
            for (int kk = 0; kk < 2; ++kk) {
                ab[nxt][kk][0] = *(const short8*)(a0 + 32 * (ks0 + kk));
                ab[nxt][kk][1] = *(const short8*)(a1 + 32 * (ks0 + kk));
                const u16* bp = w1f + (size_t)(ks0 + kk) * 4096 + (size_t)(4 * c) * 512 + lane * 8;
#pragma unroll
                for (int n = 0; n < 4; ++n) bb[nxt][kk][n] = *(const short8*)(bp + n * 512);
            }
        }
#pragma unroll
        for (int kk = 0; kk < 2; ++kk)
#pragma unroll
            for (int i = 0; i < 2; ++i)
#pragma unroll
                for (int n = 0; n < 4; ++n)
                    acc[i][n] = __builtin_amdgcn_mfma_f32_16x16x32_bf16(ab[cur][kk][i],
                                                                        bb[cur][kk][n],
                                                                        acc[i][n], 0, 0, 0);
    }

    // relu * gate -> Hm
#pragma unroll
    for (int i = 0; i < 2; ++i) {
        int rb = 32 * r + 16 * i + q * 4;
#pragma unroll
        for (int n = 0; n < 4; ++n)
#pragma unroll
            for (int rr = 0; rr < 4; ++rr)
                Hm[rb + rr][64 * c + 16 * n + m] =
                    f2bf(fmaxf(acc[i][n][rr], 0.f) * s_gate[rb + rr]);
    }

    // GEMM2: wave owns cols [128*wv, 128*wv+128); all 32 B-frags issued before barrier
    short8 cb[4][8];
#pragma unroll
    for (int ks = 0; ks < 4; ++ks) {
        const u16* bp = w2f + (size_t)(ks * 32 + wv * 8) * 512 + lane * 8;
#pragma unroll
        for (int n = 0; n < 8; ++n) cb[ks][n] = *(const short8*)(bp + n * 512);
    }
    __syncthreads();                                // Hm ready

#pragma unroll
    for (int half = 0; half < 2; ++half) {
        f32x4 acc2[2][8];
#pragma unroll
        for (int i = 0; i < 2; ++i)
#pragma unroll
            for (int n = 0; n < 8; ++n) acc2[i][n] = (f32x4){0.f, 0.f, 0.f, 0.f};
#pragma unroll
        for (int ks = 0; ks < 4; ++ks) {
            short8 h0 = *(const short8*)&Hm[32 * half + m][32 * ks + q * 8];
            short8 h1 = *(const short8*)&Hm[32 * half + 16 + m][32 * ks + q * 8];
#pragma unroll
            for (int n = 0; n < 8; ++n) {
                acc2[0][n] = __builtin_amdgcn_mfma_f32_16x16x32_bf16(h0, cb[ks][n], acc2[0][n], 0, 0, 0);
                acc2[1][n] = __builtin_amdgcn_mfma_f32_16x16x32_bf16(h1, cb[ks][n], acc2[1][n], 0, 0, 0);
            }
        }
#pragma unroll
        for (int i = 0; i < 2; ++i) {
            int rb = 32 * half + 16 * i + q * 4;
#pragma unroll
            for (int rr = 0; rr < 4; ++rr) {
                int rl = rb + rr;
                if (rl < rows) {
                    int en = s_ent[rl];
                    int tk = en & 0xFFFF, sl = en >> 16;
                    if (use_part) {
                        u16* pp = part + ((size_t)sl * NTOK + tk) * DM + 128 * wv + m;
#pragma unroll
                        for (int n = 0; n < 8; ++n) pp[16 * n] = f2bf(acc2[i][n][rr]);
                    } else {
                        float* op = out + (size_t)tk * DM + 128 * wv + m;
#pragma unroll
                        for (int n = 0; n < 8; ++n) atomicAdd(&op[16 * n], acc2[i][n][rr]);
                    }
                }
            }
        }
    }
}

// ---------------- combine: out[t][c] = sum_k part[k][t][c] ----------------
__global__ __launch_bounds__(256) void combine_kernel(const u16* __restrict__ part,
                                                      float* __restrict__ out) {
    size_t off = ((size_t)blockIdx.x * 256 + threadIdx.x) * 8;
    float s[8] = {0, 0, 0, 0, 0, 0, 0, 0};
#pragma unroll
    for (int k = 0; k < TK; ++k) {
        u16x8 p = *(const u16x8*)(part + (size_t)k * NTOK * DM + off);
#pragma unroll
        for (int j = 0; j < 8; ++j) s[j] += bf2f(p[j]);
    }
    *(f32x4*)(out + off)     = (f32x4){s[0], s[1], s[2], s[3]};
    *(f32x4*)(out + off + 4) = (f32x4){s[4], s[5], s[6], s[7]};
}

extern "C" void kernel_launch(void* const* d_in, const int* in_sizes, int n_in,
                              void* d_out, int out_size, void* d_ws, size_t ws_size,
                              hipStream_t stream) {
    const float* x   = (const float*)d_in[0];   // [N, D]
    const float* sel = (const float*)d_in[1];   // [E, D]
    const float* w1  = (const float*)d_in[2];   // [E, D, H]
    const float* w2  = (const float*)d_in[3];   // [E, H, D]
    float* out = (float*)d_out;                 // [N, D]

    char* ws = (char*)d_ws;
    int*   counts    = (int*)(ws);                                   // 256B
    int*   tok_list  = (int*)(ws + 2048);                            // 512KB (slot<<16 | tok)
    float* gate_list = (float*)(ws + 2048 + (size_t)NE * NTOK * 4);  // 512KB
    u16*   xbf  = (u16*)(ws + 2048 + (size_t)NE * NTOK * 8);         // 4MB
    u16*   wf1  = xbf + (size_t)NTOK * DM;                           // 4MB
    u16*   wf2  = wf1 + (size_t)NE * HD * DM;                        // 4MB
    u16*   part = wf2 + (size_t)NE * HD * DM;                        // 16.8MB (optional)

    size_t need = 2048 + (size_t)NE * NTOK * 8 + (size_t)NTOK * DM * 2
                + 2 * (size_t)NE * HD * DM * 2 + (size_t)TK * NTOK * DM * 2;
    int use_part = (ws_size >= need) ? 1 : 0;

    hipMemsetAsync(counts, 0, 256, stream);
    if (!use_part)
        hipMemsetAsync(d_out, 0, (size_t)NTOK * DM * sizeof(float), stream);

    prep_kernel<<<2304, 256, 0, stream>>>(x, sel, w1, w2, counts, tok_list, gate_list,
                                          xbf, wf1, wf2);
    moe_mlp_kernel<<<288, 256, 0, stream>>>(xbf, wf1, wf2, counts, tok_list, gate_list,
                                            part, out, use_part);
    if (use_part)
        combine_kernel<<<NTOK * DM / 8 / 256, 256, 0, stream>>>(part, out);
}